// Round 2
// baseline (1193.285 us; speedup 1.0000x reference)
//
#include <hip/hip_runtime.h>

// out[b,o,i] = sum_c x[b,c,i] * W[i,o,c] + bias[i,o]
//   x:   [64, 256, 2048] fp32
//   W:   [2048, 256, 256] fp32   (o-major, c contiguous -> perfect B^T MFMA feed)
//   bias:[2048, 256] fp32
//   out: [64, 256, 2048] fp32
//
// Memory-bound: ~807 MB/dispatch ideal, floor ~128 us @ 6.3 TB/s.
//
// R2: full-line output writes. R1 post-mortem showed WRITE_SIZE 5x ideal:
// with PP=2, each 64B out line (16 positions) is written 8B at a time by 8
// WGs, and the active partial-line footprint per XCD (64b*256o*8lines*64B =
// 8MB) exceeds the 4MB L2 while W streams through it -> partial evictions.
// Fix: each WG owns IPC=16 consecutive positions = exactly one 64B line per
// (b,o). Tile shrinks to M=32 x N=64 x 16pos so acc stays 128 VGPRs.
//   grid = 128 i-chunks x 4 n-slices x 2 m-halves = 1024 WGs x 256 thr.
// x staged 2 positions/round (8 rounds, fully unrolled -> static acc idx);
// x line re-reads across rounds served by L2/L3 (x total 134MB < 256MB L3).
// W read by both m-halves of a chunk -> adjacent WGs on same XCD -> L2 hit
// (NT hint removed: L2's only retention job now is W-dup + x-dup).
// All out/x/W lines are chunk-exclusive -> zero cross-XCD line sharing.

constexpr int NPOS = 2048;
constexpr int CIN  = 256;
constexpr int COUT = 256;
constexpr int NB   = 64;   // batch
constexpr int IPC  = 16;   // positions per WG = one 64B out line
constexpr int MH   = 32;   // batches per WG
constexpr int NC   = 64;   // couts per WG
constexpr int XS_STRIDE = 264;  // CIN + 8 pad
constexpr int NWG  = (NPOS/IPC) * (COUT/NC) * (NB/MH);  // 128*4*2 = 1024
constexpr int NXCD = 8;
constexpr int CPX  = NWG / NXCD;  // 128 (1024 % 8 == 0 -> bijective swizzle)

typedef short short8 __attribute__((ext_vector_type(8)));
typedef float f32x4  __attribute__((ext_vector_type(4)));

__device__ __forceinline__ unsigned short f2bf(float f) {
  // round-to-nearest-even fp32 -> bf16 (inputs finite; no NaN handling)
  unsigned int u = __builtin_bit_cast(unsigned int, f);
  u += 0x7FFFu + ((u >> 16) & 1u);
  return (unsigned short)(u >> 16);
}

__global__ __launch_bounds__(256, 2)
void fc_kernel(const float* __restrict__ X, const float* __restrict__ W,
               const float* __restrict__ Bv, float* __restrict__ Out) {
  __shared__ __align__(16) unsigned short xs[2 * MH * XS_STRIDE];  // 33.8 KB

  const int tid = threadIdx.x;
  const int bid = blockIdx.x;

  // XCD swizzle: XCD k gets logical blocks [k*CPX,(k+1)*CPX) -> 16 contiguous
  // position-chunks; all 8 WGs of a chunk land adjacent on one XCD.
  const int lb = (bid & (NXCD - 1)) * CPX + (bid >> 3);
  const int chunk  = lb >> 3;        // 0..127   position chunk (16 pos)
  const int nslice = (lb >> 1) & 3;  // 0..3     cout slice (64 couts)
  const int mhalf  = lb & 1;         // 0..1     batch half (32 b)
  const int i0     = chunk * IPC;
  const int m_base = mhalf * MH;

  const int lane = tid & 63;
  const int wave = tid >> 6;
  const int lr = lane & 15;   // row-within-16
  const int q  = lane >> 4;   // quad
  const int n0 = nslice * NC + wave * 16;  // this wave's 16 couts
  const int o  = n0 + lr;

  f32x4 acc[IPC][2] = {};   // [pos][m-tile], 128 VGPRs

  #pragma unroll
  for (int s = 0; s < IPC / 2; ++s) {
    if (s) __syncthreads();  // protect previous round's xs reads

    // ---- stage x[m_base..+31, c, i0+2s .. +1] -> xs[p][bi][c] as bf16 ----
    {
      const int c = tid;  // 0..255 == CIN
      #pragma unroll 4
      for (int bi = 0; bi < MH; ++bi) {
        const float2 v = *(const float2*)(
            X + ((size_t)((m_base + bi) * CIN + c)) * NPOS + i0 + 2 * s);
        xs[(0 * MH + bi) * XS_STRIDE + c] = f2bf(v.x);
        xs[(1 * MH + bi) * XS_STRIDE + c] = f2bf(v.y);
      }
    }
    __syncthreads();

    const float* Wp0 = W + ((size_t)(i0 + 2 * s    ) * COUT + o) * CIN;
    const float* Wp1 = W + ((size_t)(i0 + 2 * s + 1) * COUT + o) * CIN;

    #pragma unroll
    for (int k0 = 0; k0 < CIN; k0 += 32) {
      const int kk = k0 + q * 8;
      #pragma unroll
      for (int p = 0; p < 2; ++p) {
        // B-fragment: W[i][o][kk..kk+7] (32B contiguous per lane)
        const float* wp = (p ? Wp1 : Wp0) + kk;
        const f32x4 w0 = *(const f32x4*)wp;
        const f32x4 w1 = *(const f32x4*)(wp + 4);
        short8 bb;
        bb[0] = (short)f2bf(w0[0]); bb[1] = (short)f2bf(w0[1]);
        bb[2] = (short)f2bf(w0[2]); bb[3] = (short)f2bf(w0[3]);
        bb[4] = (short)f2bf(w1[0]); bb[5] = (short)f2bf(w1[1]);
        bb[6] = (short)f2bf(w1[2]); bb[7] = (short)f2bf(w1[3]);
        #pragma unroll
        for (int tm = 0; tm < 2; ++tm) {
          // A-fragment: xs[p][tm*16+lr][kk..kk+7]
          const short8 a = *(const short8*)
              &xs[(p * MH + tm * 16 + lr) * XS_STRIDE + kk];
          acc[2 * s + p][tm] = __builtin_amdgcn_mfma_f32_16x16x32_bf16(
              a, bb, acc[2 * s + p][tm], 0, 0, 0);
        }
      }
    }
  }

  // ---- epilogue: + bias, full 64B-line stores along i ----
  // D mapping: row(m=batch) = q*4 + r, col(n=cout) = lr
  float bv[IPC];
  #pragma unroll
  for (int ii = 0; ii < IPC; ++ii)
    bv[ii] = Bv[(size_t)(i0 + ii) * COUT + o];

  #pragma unroll
  for (int tm = 0; tm < 2; ++tm) {
    #pragma unroll
    for (int r = 0; r < 4; ++r) {
      const int b = m_base + tm * 16 + q * 4 + r;
      float* op = Out + ((size_t)(b * COUT + o)) * NPOS + i0;
      #pragma unroll
      for (int j = 0; j < 4; ++j) {
        f32x4 v;
        v[0] = acc[4 * j + 0][tm][r] + bv[4 * j + 0];
        v[1] = acc[4 * j + 1][tm][r] + bv[4 * j + 1];
        v[2] = acc[4 * j + 2][tm][r] + bv[4 * j + 2];
        v[3] = acc[4 * j + 3][tm][r] + bv[4 * j + 3];
        *(f32x4*)(op + 4 * j) = v;  // 4x16B back-to-back = full-line dirty
      }
    }
  }
}

extern "C" void kernel_launch(void* const* d_in, const int* in_sizes, int n_in,
                              void* d_out, int out_size, void* d_ws, size_t ws_size,
                              hipStream_t stream) {
  const float* X  = (const float*)d_in[0];
  const float* W  = (const float*)d_in[1];
  const float* Bv = (const float*)d_in[2];
  float* Out = (float*)d_out;
  dim3 grid(NWG);
  dim3 block(256);
  fc_kernel<<<grid, block, 0, stream>>>(X, W, Bv, Out);
}

// Round 3
// 1046.307 us; speedup vs baseline: 1.1405x; 1.1405x over previous
//
#include <hip/hip_runtime.h>

// out[b,o,i] = sum_c x[b,c,i] * W[i,o,c] + bias[i,o]
//   x:   [64, 256, 2048] fp32
//   W:   [2048, 256, 256] fp32   (o-major, c contiguous -> perfect B^T MFMA feed)
//   bias:[2048, 256] fp32
//   out: [64, 256, 2048] fp32
//
// R3: two-kernel plan.
//  Post-mortem R2: full-line writes fixed WRITE (672->205MB) but FETCH blew up
//  to 1.44GB = W x2 (m-half WGs drift > 12us L2 turnover) + x line re-reads
//  (8B-of-64B per round, L3 turnover too fast). BW pinned ~2.7TB/s by the
//  stride-8KB float2 gathers (64 lines per load instr) + barrier convoys.
//  Fix: (1) pre-kernel transposes x -> xT[i][b][c] bf16 in d_ws: reads each
//  x line exactly once (full 64B per thread), writes coalesced. (2) main
//  kernel has NO LDS and NO barriers: A-fragments load straight from xT
//  (contiguous 32KB/position panels), W streamed once per WG (m-halves are
//  waves of the SAME WG -> same-CU L1/L2 reuse), full-line out writes.

constexpr int NPOS = 2048;
constexpr int CIN  = 256;
constexpr int COUT = 256;
constexpr int NB   = 64;    // batch
constexpr int IPC  = 16;    // positions per WG = one 64B out line per (b,o)
constexpr size_t XT_BYTES = (size_t)NPOS * NB * CIN * 2;  // 67.1 MB bf16

constexpr int NXCD = 8;

typedef short short8 __attribute__((ext_vector_type(8)));
typedef float f32x4  __attribute__((ext_vector_type(4)));

__device__ __forceinline__ unsigned short f2bf(float f) {
  // round-to-nearest-even fp32 -> bf16 (inputs finite; no NaN handling)
  unsigned int u = __builtin_bit_cast(unsigned int, f);
  u += 0x7FFFu + ((u >> 16) & 1u);
  return (unsigned short)(u >> 16);
}

// ---------------------------------------------------------------------------
// Pre-kernel: x[b][c][i] f32 -> xT[i][b][c] bf16.
// WG tile: 16 i x 8 b x 256 c. Thread t, row k (k=0..7): (b,c) = (b0+k, t);
// reads the FULL 64B line x[b][c][i0..i0+15] (4x f32x4), LDS-transposes,
// then writes xT i-rows as contiguous short8 (4KB per i-row per WG).
// ---------------------------------------------------------------------------
__global__ __launch_bounds__(256, 2)
void xpose_kernel(const float* __restrict__ X, unsigned short* __restrict__ XT) {
  __shared__ __align__(16) unsigned short tile[16 * 8 * 264];  // [i][b'][c] 67.6KB

  const int tid = threadIdx.x;
  const int bid = blockIdx.x;
  const int it  = bid >> 3;          // 0..127  i-tile
  const int b0  = (bid & 7) * 8;     // 0..56   b-tile base
  const int i0  = it * 16;

  #pragma unroll
  for (int k = 0; k < 8; ++k) {
    const int b = b0 + k;
    const int c = tid;
    const float* p = X + ((size_t)(b * CIN + c)) * NPOS + i0;
    const f32x4 v0 = *(const f32x4*)(p + 0);
    const f32x4 v1 = *(const f32x4*)(p + 4);
    const f32x4 v2 = *(const f32x4*)(p + 8);
    const f32x4 v3 = *(const f32x4*)(p + 12);
    #pragma unroll
    for (int j = 0; j < 4; ++j) {
      tile[((4 * 0 + j) * 8 + k) * 264 + c] = f2bf(v0[j]);
      tile[((4 * 1 + j) * 8 + k) * 264 + c] = f2bf(v1[j]);
      tile[((4 * 2 + j) * 8 + k) * 264 + c] = f2bf(v2[j]);
      tile[((4 * 3 + j) * 8 + k) * 264 + c] = f2bf(v3[j]);
    }
  }
  __syncthreads();

  const int bp = tid >> 5;          // 0..7  b'
  const int c0 = (tid & 31) * 8;    // 0..248
  #pragma unroll
  for (int j = 0; j < 16; ++j) {
    const short8 v = *(const short8*)&tile[(j * 8 + bp) * 264 + c0];
    *(short8*)(XT + ((size_t)(i0 + j) * NB + b0 + bp) * CIN + c0) = v;
  }
}

// ---------------------------------------------------------------------------
// Main kernel: no LDS, no barriers. 256 thr = 4 waves: mh = wave>>1 (32 b),
// nh = wave&1 (16 couts). WG tile M=64 x N=32 x IPC=16; acc = 128 VGPRs.
// Grid = 128 chunks x 8 n-slices = 1024 WGs; XCD swizzle keeps a chunk's 8
// WGs on one XCD (x panel 512KB L2-shared; W rows unique per WG).
// ---------------------------------------------------------------------------
__global__ __launch_bounds__(256, 2)
void fc_main(const unsigned short* __restrict__ XT, const float* __restrict__ W,
             const float* __restrict__ Bv, float* __restrict__ Out) {
  const int bid = blockIdx.x;
  // bijective XCD swizzle (1024 % 8 == 0): XCD k owns chunks [16k, 16k+16)
  const int lb  = (bid & (NXCD - 1)) * 128 + (bid >> 3);
  const int chunk = lb >> 3;        // 0..127
  const int nsl   = lb & 7;         // 0..7
  const int i0    = chunk * IPC;

  const int tid  = threadIdx.x;
  const int lane = tid & 63;
  const int wave = tid >> 6;
  const int lr = lane & 15;   // row-within-16
  const int q  = lane >> 4;   // quad
  const int mh = wave >> 1;   // m-half (32 batches)
  const int nh = wave & 1;    // n-half (16 couts)
  const int m_base = mh * 32;
  const int o  = nsl * 32 + nh * 16 + lr;   // this lane's cout row

  f32x4 acc[IPC][2] = {};   // [pos][m-tile], 128 VGPRs

  #pragma unroll
  for (int s = 0; s < IPC / 2; ++s) {
    const int ia = i0 + 2 * s;
    const unsigned short* A0 = XT + ((size_t)(ia + 0) * NB + m_base) * CIN;
    const unsigned short* A1 = XT + ((size_t)(ia + 1) * NB + m_base) * CIN;
    const float* Wp0 = W + ((size_t)(ia + 0) * COUT + o) * CIN;
    const float* Wp1 = W + ((size_t)(ia + 1) * COUT + o) * CIN;

    #pragma unroll
    for (int k0 = 0; k0 < CIN; k0 += 32) {
      const int kk = k0 + q * 8;
      #pragma unroll
      for (int p = 0; p < 2; ++p) {
        // B-fragment: W[i][o][kk..kk+7], 32B contiguous per lane
        const float* wp = (p ? Wp1 : Wp0) + kk;
        const f32x4 w0 = *(const f32x4*)wp;
        const f32x4 w1 = *(const f32x4*)(wp + 4);
        short8 bb;
        bb[0] = (short)f2bf(w0[0]); bb[1] = (short)f2bf(w0[1]);
        bb[2] = (short)f2bf(w0[2]); bb[3] = (short)f2bf(w0[3]);
        bb[4] = (short)f2bf(w1[0]); bb[5] = (short)f2bf(w1[1]);
        bb[6] = (short)f2bf(w1[2]); bb[7] = (short)f2bf(w1[3]);
        const unsigned short* Ap = (p ? A1 : A0);
        #pragma unroll
        for (int tm = 0; tm < 2; ++tm) {
          // A-fragment: xT[i][m_base + tm*16 + lr][kk..kk+7], 16B/lane
          const short8 a = *(const short8*)(Ap + (tm * 16 + lr) * CIN + kk);
          acc[2 * s + p][tm] = __builtin_amdgcn_mfma_f32_16x16x32_bf16(
              a, bb, acc[2 * s + p][tm], 0, 0, 0);
        }
      }
    }
  }

  // ---- epilogue: + bias, full 64B-line stores along i ----
  // D mapping: row(m=batch) = q*4 + r, col(n=cout) = lr
  float bv[IPC];
  #pragma unroll
  for (int ii = 0; ii < IPC; ++ii)
    bv[ii] = Bv[(size_t)(i0 + ii) * COUT + o];

  #pragma unroll
  for (int tm = 0; tm < 2; ++tm) {
    #pragma unroll
    for (int r = 0; r < 4; ++r) {
      const int b = m_base + tm * 16 + q * 4 + r;
      float* op = Out + ((size_t)(b * COUT + o)) * NPOS + i0;
      #pragma unroll
      for (int j = 0; j < 4; ++j) {
        f32x4 v;
        v[0] = acc[4 * j + 0][tm][r] + bv[4 * j + 0];
        v[1] = acc[4 * j + 1][tm][r] + bv[4 * j + 1];
        v[2] = acc[4 * j + 2][tm][r] + bv[4 * j + 2];
        v[3] = acc[4 * j + 3][tm][r] + bv[4 * j + 3];
        *(f32x4*)(op + 4 * j) = v;  // 4x16B back-to-back = full-line dirty
      }
    }
  }
}

// ---------------------------------------------------------------------------
// Fallback (ws too small): R1 kernel, known-good 408us/dispatch.
// ---------------------------------------------------------------------------
constexpr int PP = 2;
constexpr int XS_STRIDE = 264;

__global__ __launch_bounds__(256, 2)
void fc_fallback(const float* __restrict__ X, const float* __restrict__ W,
                 const float* __restrict__ Bv, float* __restrict__ Out) {
  __shared__ __align__(16) unsigned short xs[PP * NB * XS_STRIDE];
  const int tid = threadIdx.x;
  const int bid = blockIdx.x;
  const int lb  = (bid & (NXCD - 1)) * 128 + (bid >> 3);
  const int i0  = lb * PP;

  {
    const int c = tid;
    #pragma unroll 4
    for (int b = 0; b < NB; ++b) {
      const float2 v = *(const float2*)(X + ((b * CIN + c) * NPOS + i0));
      xs[(0 * NB + b) * XS_STRIDE + c] = f2bf(v.x);
      xs[(1 * NB + b) * XS_STRIDE + c] = f2bf(v.y);
    }
  }
  __syncthreads();

  const int lane = tid & 63;
  const int wave = tid >> 6;
  const int lr = lane & 15;
  const int q  = lane >> 4;
  const int n0 = wave * 64;

  f32x4 acc[PP][4][4] = {};
  const float* W0 = W + (size_t)(i0 + 0) * (COUT * CIN);
  const float* W1 = W + (size_t)(i0 + 1) * (COUT * CIN);

  for (int k0 = 0; k0 < CIN; k0 += 32) {
    const int kk = k0 + q * 8;
    short8 a[PP][4];
    #pragma unroll
    for (int p = 0; p < PP; ++p)
      #pragma unroll
      for (int tm = 0; tm < 4; ++tm)
        a[p][tm] = *(const short8*)&xs[(p * NB + tm * 16 + lr) * XS_STRIDE + kk];

    #pragma unroll
    for (int p = 0; p < PP; ++p) {
      const float* Wi = (p == 0) ? W0 : W1;
      #pragma unroll
      for (int tn = 0; tn < 4; ++tn) {
        const float* wp = Wi + (n0 + tn * 16 + lr) * CIN + kk;
        const f32x4 w0 = *(const f32x4*)wp;
        const f32x4 w1 = *(const f32x4*)(wp + 4);
        short8 bb;
        bb[0] = (short)f2bf(w0[0]); bb[1] = (short)f2bf(w0[1]);
        bb[2] = (short)f2bf(w0[2]); bb[3] = (short)f2bf(w0[3]);
        bb[4] = (short)f2bf(w1[0]); bb[5] = (short)f2bf(w1[1]);
        bb[6] = (short)f2bf(w1[2]); bb[7] = (short)f2bf(w1[3]);
        #pragma unroll
        for (int tm = 0; tm < 4; ++tm)
          acc[p][tm][tn] = __builtin_amdgcn_mfma_f32_16x16x32_bf16(
              a[p][tm], bb, acc[p][tm][tn], 0, 0, 0);
      }
    }
  }

  #pragma unroll
  for (int tn = 0; tn < 4; ++tn) {
    const int o = n0 + tn * 16 + lr;
    const float bv0 = Bv[(i0 + 0) * COUT + o];
    const float bv1 = Bv[(i0 + 1) * COUT + o];
    #pragma unroll
    for (int tm = 0; tm < 4; ++tm) {
      #pragma unroll
      for (int r = 0; r < 4; ++r) {
        const int b = tm * 16 + q * 4 + r;
        float2 v;
        v.x = acc[0][tm][tn][r] + bv0;
        v.y = acc[1][tm][tn][r] + bv1;
        *(float2*)(Out + ((b * COUT + o) * NPOS + i0)) = v;
      }
    }
  }
}

extern "C" void kernel_launch(void* const* d_in, const int* in_sizes, int n_in,
                              void* d_out, int out_size, void* d_ws, size_t ws_size,
                              hipStream_t stream) {
  const float* X  = (const float*)d_in[0];
  const float* W  = (const float*)d_in[1];
  const float* Bv = (const float*)d_in[2];
  float* Out = (float*)d_out;

  if (d_ws != nullptr && ws_size >= XT_BYTES) {
    unsigned short* XT = (unsigned short*)d_ws;
    xpose_kernel<<<dim3(128 * 8), dim3(256), 0, stream>>>(X, XT);
    fc_main<<<dim3(1024), dim3(256), 0, stream>>>(XT, W, Bv, Out);
  } else {
    fc_fallback<<<dim3(1024), dim3(256), 0, stream>>>(X, W, Bv, Out);
  }
}